// Round 1
// baseline (814.384 us; speedup 1.0000x reference)
//
#include <hip/hip_runtime.h>

#define N_EDGES 800000
#define D 64

// One wave = 4 edges. Within a wave: group g (16 lanes) owns edge 4q+g;
// lane-in-group lg owns outputs [4*lg, 4*lg+4).
// Per k-step: feat broadcast float4 + 4 coalesced float4 W loads + 16 FMAs/lane.
__global__ __launch_bounds__(256) void rgcn_edge_kernel(
    const float* __restrict__ feat,
    const float* __restrict__ weight,
    const int*   __restrict__ src,
    const int*   __restrict__ dst,
    const int*   __restrict__ et,
    float*       __restrict__ out,
    int nquads)
{
    const int tid  = blockIdx.x * blockDim.x + threadIdx.x;
    const int wave = tid >> 6;
    const int lane = tid & 63;
    const int grp  = lane >> 4;   // which edge of the quad
    const int lg   = lane & 15;   // output group: 4 outputs per lane

    const int wave_stride = (gridDim.x * blockDim.x) >> 6;

    for (int q = wave; q < nquads; q += wave_stride) {
        const int e = q * 4 + grp;
        const int s = src[e];
        const int d = dst[e];
        const int r = et[e];

        const float* __restrict__ frow = feat + (size_t)s * D;
        const float* __restrict__ w    = weight + (size_t)r * D * D + lg * 4;

        float ax = 0.f, ay = 0.f, az = 0.f, aw = 0.f;

        #pragma unroll
        for (int i4 = 0; i4 < D / 4; ++i4) {
            const float4 f  = *reinterpret_cast<const float4*>(frow + i4 * 4);
            const float4 w0 = *reinterpret_cast<const float4*>(w + (i4 * 4 + 0) * D);
            const float4 w1 = *reinterpret_cast<const float4*>(w + (i4 * 4 + 1) * D);
            const float4 w2 = *reinterpret_cast<const float4*>(w + (i4 * 4 + 2) * D);
            const float4 w3 = *reinterpret_cast<const float4*>(w + (i4 * 4 + 3) * D);

            ax += f.x * w0.x; ay += f.x * w0.y; az += f.x * w0.z; aw += f.x * w0.w;
            ax += f.y * w1.x; ay += f.y * w1.y; az += f.y * w1.z; aw += f.y * w1.w;
            ax += f.z * w2.x; ay += f.z * w2.y; az += f.z * w2.z; aw += f.z * w2.w;
            ax += f.w * w3.x; ay += f.w * w3.y; az += f.w * w3.z; aw += f.w * w3.w;
        }

        float* orow = out + (size_t)d * D + lg * 4;
        atomicAdd(orow + 0, ax);
        atomicAdd(orow + 1, ay);
        atomicAdd(orow + 2, az);
        atomicAdd(orow + 3, aw);
    }
}

extern "C" void kernel_launch(void* const* d_in, const int* in_sizes, int n_in,
                              void* d_out, int out_size, void* d_ws, size_t ws_size,
                              hipStream_t stream) {
    const float* feat   = (const float*)d_in[0];
    const float* weight = (const float*)d_in[1];
    const int*   src    = (const int*)d_in[2];
    const int*   dst    = (const int*)d_in[3];
    const int*   et     = (const int*)d_in[4];
    float*       out    = (float*)d_out;

    // Zero the accumulation target (graph-capturable async memset).
    hipMemsetAsync(d_out, 0, (size_t)out_size * sizeof(float), stream);

    const int nquads = N_EDGES / 4;  // 800000 % 4 == 0
    const int blocks = 4096;         // grid-stride, ~12 quads per wave
    hipLaunchKernelGGL(rgcn_edge_kernel, dim3(blocks), dim3(256), 0, stream,
                       feat, weight, src, dst, et, out, nquads);
}

// Round 2
// 346.298 us; speedup vs baseline: 2.3517x; 2.3517x over previous
//
#include <hip/hip_runtime.h>
#include <hip/hip_bf16.h>

#define N_NODES 50000
#define N_EDGES 800000
#define N_RELS  32
#define D       64
#define TILE_M  256

typedef _Float16 half8 __attribute__((ext_vector_type(8)));
typedef float    f32x4 __attribute__((ext_vector_type(4)));
typedef short    short8 __attribute__((ext_vector_type(8)));

// ---------------- workspace layout (bytes) ----------------
#define OFF_RELHIST 0u          // 32 int
#define OFF_RELCUR  128u        // 32 int
#define OFF_ROFF    256u        // 33 int
#define OFF_TB      512u        // 33 int
#define OFF_COUNTS  768u        // 50000 int
#define OFF_DSTOFF  200960u     // 50001 int
#define OFF_DSTCUR  401152u     // 50000 int
#define OFF_RELSRC  601344u     // 800000 int
#define OFF_CSRY    3801344u    // 800000 int
#define OFF_WT      7001344u    // 32*64*64 fp16
#define OFF_Y       7263488u    // 800000*64 fp16
#define WS_REQ      109663488u

// ---------------- fallback: round-1 atomic kernel ----------------
__global__ __launch_bounds__(256) void rgcn_edge_atomic(
    const float* __restrict__ feat, const float* __restrict__ weight,
    const int* __restrict__ src, const int* __restrict__ dst,
    const int* __restrict__ et, float* __restrict__ out, int nquads)
{
    const int tid  = blockIdx.x * blockDim.x + threadIdx.x;
    const int wave = tid >> 6, lane = tid & 63;
    const int grp = lane >> 4, lg = lane & 15;
    const int wave_stride = (gridDim.x * blockDim.x) >> 6;
    for (int q = wave; q < nquads; q += wave_stride) {
        const int e = q * 4 + grp;
        const int s = src[e], d = dst[e], r = et[e];
        const float* frow = feat + (size_t)s * D;
        const float* w = weight + (size_t)r * D * D + lg * 4;
        float ax = 0.f, ay = 0.f, az = 0.f, aw = 0.f;
        #pragma unroll
        for (int i4 = 0; i4 < D / 4; ++i4) {
            const float4 f  = *reinterpret_cast<const float4*>(feat + (size_t)s * D + i4 * 4);
            const float4 w0 = *reinterpret_cast<const float4*>(w + (i4 * 4 + 0) * D);
            const float4 w1 = *reinterpret_cast<const float4*>(w + (i4 * 4 + 1) * D);
            const float4 w2 = *reinterpret_cast<const float4*>(w + (i4 * 4 + 2) * D);
            const float4 w3 = *reinterpret_cast<const float4*>(w + (i4 * 4 + 3) * D);
            ax += f.x*w0.x; ay += f.x*w0.y; az += f.x*w0.z; aw += f.x*w0.w;
            ax += f.y*w1.x; ay += f.y*w1.y; az += f.y*w1.z; aw += f.y*w1.w;
            ax += f.z*w2.x; ay += f.z*w2.y; az += f.z*w2.z; aw += f.z*w2.w;
            ax += f.w*w3.x; ay += f.w*w3.y; az += f.w*w3.z; aw += f.w*w3.w;
        }
        float* orow = out + (size_t)d * D + lg * 4;
        atomicAdd(orow + 0, ax); atomicAdd(orow + 1, ay);
        atomicAdd(orow + 2, az); atomicAdd(orow + 3, aw);
    }
}

// ---------------- K0: W -> W^T fp16 (wT[r][o][k]) ----------------
__global__ __launch_bounds__(256) void k0_wt(const float* __restrict__ w,
                                             _Float16* __restrict__ wT)
{
    const int r = blockIdx.x, t = threadIdx.x;
    #pragma unroll
    for (int i = 0; i < 16; ++i) {
        int oidx = i * 256 + t;            // 0..4095 = o*64+k (output-coalesced)
        int o = oidx >> 6, k = oidx & 63;
        wT[(size_t)r * 4096 + oidx] = (_Float16)w[(size_t)r * 4096 + k * 64 + o];
    }
}

// ---------------- K1: histograms (rel via LDS, dst direct) ----------------
__global__ __launch_bounds__(256) void k1_hist(const int* __restrict__ et,
                                               const int* __restrict__ dst,
                                               int* __restrict__ relhist,
                                               int* __restrict__ counts)
{
    __shared__ int lh[N_RELS];
    const int t = threadIdx.x;
    if (t < N_RELS) lh[t] = 0;
    __syncthreads();
    const int e = blockIdx.x * 256 + t;
    atomicAdd(&lh[et[e]], 1);
    atomicAdd(&counts[dst[e]], 1);
    __syncthreads();
    if (t < N_RELS && lh[t] > 0) atomicAdd(&relhist[t], lh[t]);
}

// ---------------- K2: scans (rel offsets + tile table + dst offsets) ------
__global__ __launch_bounds__(1024) void k2_scan(const int* __restrict__ relhist,
                                                const int* __restrict__ counts,
                                                int* __restrict__ roff,
                                                int* __restrict__ relcur,
                                                int* __restrict__ tb,
                                                int* __restrict__ dst_off,
                                                int* __restrict__ dstcur)
{
    __shared__ int lds[1024];
    const int t = threadIdx.x;
    if (t == 0) {
        int run = 0, trun = 0;
        for (int r = 0; r < N_RELS; ++r) {
            roff[r] = run; relcur[r] = run; tb[r] = trun;
            int c = relhist[r];
            run += c; trun += (c + TILE_M - 1) / TILE_M;
        }
        roff[N_RELS] = run; tb[N_RELS] = trun;
    }
    const int CHUNK = 49;                  // 49*1024 >= 50000
    int lo = t * CHUNK, hi = min(lo + CHUNK, N_NODES);
    int s = 0;
    for (int i = lo; i < hi; ++i) s += counts[i];
    lds[t] = s;
    __syncthreads();
    for (int off = 1; off < 1024; off <<= 1) {
        int v = (t >= off) ? lds[t - off] : 0;
        __syncthreads();
        lds[t] += v;
        __syncthreads();
    }
    int base = (t == 0) ? 0 : lds[t - 1];
    for (int i = lo; i < hi; ++i) {
        dst_off[i] = base; dstcur[i] = base;
        base += counts[i];
    }
    if (t == 1023) dst_off[N_NODES] = lds[1023];
}

// ---------------- K3: scatter (rel-sorted src list + dst CSR of Y ids) ----
__global__ __launch_bounds__(256) void k3_scatter(const int* __restrict__ src,
                                                  const int* __restrict__ dst,
                                                  const int* __restrict__ et,
                                                  int* __restrict__ relcur,
                                                  int* __restrict__ dstcur,
                                                  int* __restrict__ relsrc,
                                                  int* __restrict__ csr_y)
{
    __shared__ int lh[N_RELS];
    __shared__ int lbase[N_RELS];
    const int t = threadIdx.x;
    if (t < N_RELS) lh[t] = 0;
    __syncthreads();
    const int e = blockIdx.x * 256 + t;
    const int r = et[e], s = src[e], d = dst[e];
    const int slot = atomicAdd(&lh[r], 1);
    __syncthreads();
    if (t < N_RELS && lh[t] > 0) lbase[t] = atomicAdd(&relcur[t], lh[t]);
    __syncthreads();
    const int j = lbase[r] + slot;
    relsrc[j] = s;
    const int p = atomicAdd(&dstcur[d], 1);
    csr_y[p] = j;
}

// ---------------- K4: per-relation GEMM via MFMA -> Y fp16 ----------------
__global__ __launch_bounds__(256) void k4_gemm(const float* __restrict__ feat,
                                               const _Float16* __restrict__ wT,
                                               const int* __restrict__ relsrc,
                                               const int* __restrict__ roff,
                                               const int* __restrict__ tb,
                                               _Float16* __restrict__ Y)
{
    __shared__ _Float16 aT[TILE_M * 64];   // XOR-swizzled [row][k]
    __shared__ _Float16 wL[64 * 64];       // XOR-swizzled [out][k] (W^T)
    const int b = blockIdx.x, t = threadIdx.x;

    int r = -1, ti = 0, t0 = 0;
    #pragma unroll
    for (int q = 0; q < N_RELS; ++q) {
        int t1 = tb[q + 1];
        if (b >= t0 && b < t1) { r = q; ti = b - t0; }
        t0 = t1;
    }
    if (r < 0) return;
    const int segstart = roff[r], segend = roff[r + 1];
    const int rowbase = segstart + ti * TILE_M;

    // stage W^T (already fp16, contiguous) into swizzled LDS
    {
        const _Float16* wsrc = wT + (size_t)r * 4096;
        #pragma unroll
        for (int it = 0; it < 2; ++it) {
            int L8 = it * 256 + t;         // chunk of 8 halves
            int o = L8 >> 3, kcol = (L8 & 7) * 8;
            int baddr = (o * 128 + kcol * 2) ^ ((o & 7) << 4);
            *reinterpret_cast<half8*>(reinterpret_cast<char*>(wL) + baddr) =
                *reinterpret_cast<const half8*>(wsrc + L8 * 8);
        }
    }
    // stage A tile: gather feat rows, convert fp32->fp16, swizzled LDS write
    {
        const int j = rowbase + t;
        const int sidx = (j < segend) ? relsrc[j] : 0;
        const float4* frow = reinterpret_cast<const float4*>(feat + (size_t)sidx * 64);
        #pragma unroll
        for (int c = 0; c < 4; ++c) {
            float4 f0 = frow[c*4+0], f1 = frow[c*4+1], f2 = frow[c*4+2], f3 = frow[c*4+3];
            half8 h0, h1;
            h0[0]=(_Float16)f0.x; h0[1]=(_Float16)f0.y; h0[2]=(_Float16)f0.z; h0[3]=(_Float16)f0.w;
            h0[4]=(_Float16)f1.x; h0[5]=(_Float16)f1.y; h0[6]=(_Float16)f1.z; h0[7]=(_Float16)f1.w;
            h1[0]=(_Float16)f2.x; h1[1]=(_Float16)f2.y; h1[2]=(_Float16)f2.z; h1[3]=(_Float16)f2.w;
            h1[4]=(_Float16)f3.x; h1[5]=(_Float16)f3.y; h1[6]=(_Float16)f3.z; h1[7]=(_Float16)f3.w;
            int base = t * 128 + c * 32;
            int a0 = (base)      ^ ((t & 7) << 4);
            int a1 = (base + 16) ^ ((t & 7) << 4);
            *reinterpret_cast<half8*>(reinterpret_cast<char*>(aT) + a0) = h0;
            *reinterpret_cast<half8*>(reinterpret_cast<char*>(aT) + a1) = h1;
        }
    }
    __syncthreads();

    const int wid = t >> 6, l = t & 63;
    const int lrow = l & 15, lkb = l >> 4;
    f32x4 acc[4][4] = {};
    #pragma unroll
    for (int ks = 0; ks < 2; ++ks) {
        half8 af[4], bfr[4];
        #pragma unroll
        for (int rt = 0; rt < 4; ++rt) {
            int row = wid * 64 + rt * 16 + lrow;
            int baddr = (row * 128 + ks * 64 + lkb * 16) ^ ((row & 7) << 4);
            af[rt] = *reinterpret_cast<const half8*>(reinterpret_cast<const char*>(aT) + baddr);
        }
        #pragma unroll
        for (int ct = 0; ct < 4; ++ct) {
            int n = ct * 16 + lrow;
            int baddr = (n * 128 + ks * 64 + lkb * 16) ^ ((n & 7) << 4);
            bfr[ct] = *reinterpret_cast<const half8*>(reinterpret_cast<const char*>(wL) + baddr);
        }
        #pragma unroll
        for (int rt = 0; rt < 4; ++rt)
            #pragma unroll
            for (int ct = 0; ct < 4; ++ct)
                acc[rt][ct] = __builtin_amdgcn_mfma_f32_16x16x32_f16(af[rt], bfr[ct], acc[rt][ct], 0, 0, 0);
    }
    // store: D layout col=lane&15, row=(lane>>4)*4+reg  [m89]
    #pragma unroll
    for (int rt = 0; rt < 4; ++rt) {
        int rowg = rowbase + wid * 64 + rt * 16 + (l >> 4) * 4;
        #pragma unroll
        for (int ct = 0; ct < 4; ++ct) {
            int col = ct * 16 + lrow;
            #pragma unroll
            for (int reg = 0; reg < 4; ++reg) {
                int row = rowg + reg;
                if (row < segend)
                    Y[(size_t)row * 64 + col] = (_Float16)acc[rt][ct][reg];
            }
        }
    }
}

// ---------------- K5: dst-CSR gather reduce (no atomics) ------------------
__global__ __launch_bounds__(256) void k5_reduce(const _Float16* __restrict__ Y,
                                                 const int* __restrict__ csr_y,
                                                 const int* __restrict__ dst_off,
                                                 float* __restrict__ out)
{
    const int wid = threadIdx.x >> 6, l = threadIdx.x & 63;
    const int n = blockIdx.x * 4 + wid;
    if (n >= N_NODES) return;
    const int p0 = dst_off[n], p1 = dst_off[n + 1];
    float acc = 0.f;
    int p = p0;
    for (; p + 4 <= p1; p += 4) {
        int ja = csr_y[p], jb = csr_y[p+1], jc = csr_y[p+2], jd = csr_y[p+3];
        float ya = (float)Y[(size_t)ja * 64 + l];
        float yb = (float)Y[(size_t)jb * 64 + l];
        float yc = (float)Y[(size_t)jc * 64 + l];
        float yd = (float)Y[(size_t)jd * 64 + l];
        acc += ya + yb + yc + yd;
    }
    for (; p < p1; ++p) {
        int j = csr_y[p];
        acc += (float)Y[(size_t)j * 64 + l];
    }
    out[(size_t)n * 64 + l] = acc;
}

extern "C" void kernel_launch(void* const* d_in, const int* in_sizes, int n_in,
                              void* d_out, int out_size, void* d_ws, size_t ws_size,
                              hipStream_t stream) {
    const float* feat   = (const float*)d_in[0];
    const float* weight = (const float*)d_in[1];
    const int*   src    = (const int*)d_in[2];
    const int*   dst    = (const int*)d_in[3];
    const int*   et     = (const int*)d_in[4];
    float*       out    = (float*)d_out;

    if (ws_size < (size_t)WS_REQ) {
        // fallback: atomic scatter path
        hipMemsetAsync(d_out, 0, (size_t)out_size * sizeof(float), stream);
        hipLaunchKernelGGL(rgcn_edge_atomic, dim3(4096), dim3(256), 0, stream,
                           feat, weight, src, dst, et, out, N_EDGES / 4);
        return;
    }

    char* ws = (char*)d_ws;
    int*       relhist = (int*)(ws + OFF_RELHIST);
    int*       relcur  = (int*)(ws + OFF_RELCUR);
    int*       roff    = (int*)(ws + OFF_ROFF);
    int*       tb      = (int*)(ws + OFF_TB);
    int*       counts  = (int*)(ws + OFF_COUNTS);
    int*       dst_off = (int*)(ws + OFF_DSTOFF);
    int*       dstcur  = (int*)(ws + OFF_DSTCUR);
    int*       relsrc  = (int*)(ws + OFF_RELSRC);
    int*       csr_y   = (int*)(ws + OFF_CSRY);
    _Float16*  wT      = (_Float16*)(ws + OFF_WT);
    _Float16*  Y       = (_Float16*)(ws + OFF_Y);

    hipMemsetAsync(relhist, 0, 128, stream);
    hipMemsetAsync(counts, 0, (size_t)N_NODES * sizeof(int), stream);

    hipLaunchKernelGGL(k0_wt,      dim3(N_RELS),        dim3(256),  0, stream, weight, wT);
    hipLaunchKernelGGL(k1_hist,    dim3(N_EDGES / 256), dim3(256),  0, stream, et, dst, relhist, counts);
    hipLaunchKernelGGL(k2_scan,    dim3(1),             dim3(1024), 0, stream, relhist, counts, roff, relcur, tb, dst_off, dstcur);
    hipLaunchKernelGGL(k3_scatter, dim3(N_EDGES / 256), dim3(256),  0, stream, src, dst, et, relcur, dstcur, relsrc, csr_y);
    const int max_tiles = N_EDGES / TILE_M + N_RELS;   // 3157 upper bound
    hipLaunchKernelGGL(k4_gemm,    dim3(max_tiles),     dim3(256),  0, stream, feat, wT, relsrc, roff, tb, Y);
    hipLaunchKernelGGL(k5_reduce,  dim3(N_NODES / 4),   dim3(256),  0, stream, Y, csr_y, dst_off, out);
}

// Round 3
// 247.972 us; speedup vs baseline: 3.2842x; 1.3965x over previous
//
#include <hip/hip_runtime.h>
#include <hip/hip_bf16.h>

#define N_NODES 50000
#define N_EDGES 800000
#define N_RELS  32
#define D       64
#define TILE_M  256
#define NSCAN_BLKS ((N_NODES + 255) / 256)   // 196

typedef _Float16 half8 __attribute__((ext_vector_type(8)));
typedef float    f32x4 __attribute__((ext_vector_type(4)));

// ---------------- workspace layout (bytes) ----------------
#define OFF_RELHIST 0u          // 32 int
#define OFF_RELCUR  128u        // 32 int
#define OFF_ROFF    256u        // 33 int
#define OFF_TB      512u        // 33 int
#define OFF_BSUM    768u        // 196 int (block sums)
#define OFF_BBASE   1600u       // 196 int (block bases)
#define OFF_COUNTS  2432u       // 50000 int
#define OFF_DSTOFF  202432u     // 50001 int
#define OFF_DSTCUR  402632u     // 50000 int
#define OFF_RELSRC  602632u     // 800000 int
#define OFF_CSRY    3802632u    // 800000 int
#define OFF_WT      7002632u    // pad to 8 -> use 7002640
#define OFF_WT_A    7002640u    // 32*64*64 fp16
#define OFF_Y       7264784u    // pad to 16 -> 7264784 (div by 16: 454049.0 -> yes /16=454049)
#define WS_REQ      109664784u

// ---------------- fallback: atomic scatter path ----------------
__global__ __launch_bounds__(256) void rgcn_edge_atomic(
    const float* __restrict__ feat, const float* __restrict__ weight,
    const int* __restrict__ src, const int* __restrict__ dst,
    const int* __restrict__ et, float* __restrict__ out, int nquads)
{
    const int tid  = blockIdx.x * blockDim.x + threadIdx.x;
    const int wave = tid >> 6, lane = tid & 63;
    const int grp = lane >> 4, lg = lane & 15;
    const int wave_stride = (gridDim.x * blockDim.x) >> 6;
    for (int q = wave; q < nquads; q += wave_stride) {
        const int e = q * 4 + grp;
        const int s = src[e], d = dst[e], r = et[e];
        const float* w = weight + (size_t)r * D * D + lg * 4;
        float ax = 0.f, ay = 0.f, az = 0.f, aw = 0.f;
        #pragma unroll
        for (int i4 = 0; i4 < D / 4; ++i4) {
            const float4 f  = *reinterpret_cast<const float4*>(feat + (size_t)s * D + i4 * 4);
            const float4 w0 = *reinterpret_cast<const float4*>(w + (i4 * 4 + 0) * D);
            const float4 w1 = *reinterpret_cast<const float4*>(w + (i4 * 4 + 1) * D);
            const float4 w2 = *reinterpret_cast<const float4*>(w + (i4 * 4 + 2) * D);
            const float4 w3 = *reinterpret_cast<const float4*>(w + (i4 * 4 + 3) * D);
            ax += f.x*w0.x; ay += f.x*w0.y; az += f.x*w0.z; aw += f.x*w0.w;
            ax += f.y*w1.x; ay += f.y*w1.y; az += f.y*w1.z; aw += f.y*w1.w;
            ax += f.z*w2.x; ay += f.z*w2.y; az += f.z*w2.z; aw += f.z*w2.w;
            ax += f.w*w3.x; ay += f.w*w3.y; az += f.w*w3.z; aw += f.w*w3.w;
        }
        float* orow = out + (size_t)d * D + lg * 4;
        atomicAdd(orow + 0, ax); atomicAdd(orow + 1, ay);
        atomicAdd(orow + 2, az); atomicAdd(orow + 3, aw);
    }
}

// ---------------- K0: W -> W^T fp16 (wT[r][o][k]) ----------------
__global__ __launch_bounds__(256) void k0_wt(const float* __restrict__ w,
                                             _Float16* __restrict__ wT)
{
    const int r = blockIdx.x, t = threadIdx.x;
    #pragma unroll
    for (int i = 0; i < 16; ++i) {
        int oidx = i * 256 + t;
        int o = oidx >> 6, k = oidx & 63;
        wT[(size_t)r * 4096 + oidx] = (_Float16)w[(size_t)r * 4096 + k * 64 + o];
    }
}

// ---------------- K1: histograms ----------------
__global__ __launch_bounds__(256) void k1_hist(const int* __restrict__ et,
                                               const int* __restrict__ dst,
                                               int* __restrict__ relhist,
                                               int* __restrict__ counts)
{
    __shared__ int lh[N_RELS];
    const int t = threadIdx.x;
    if (t < N_RELS) lh[t] = 0;
    __syncthreads();
    const int e = blockIdx.x * 256 + t;
    atomicAdd(&lh[et[e]], 1);
    atomicAdd(&counts[dst[e]], 1);
    __syncthreads();
    if (t < N_RELS && lh[t] > 0) atomicAdd(&relhist[t], lh[t]);
}

// ---------------- K2a: per-block sums of counts ----------------
__global__ __launch_bounds__(256) void k2a_bsum(const int* __restrict__ counts,
                                                int* __restrict__ bsum)
{
    __shared__ int lds[256];
    const int t = threadIdx.x;
    const int i = blockIdx.x * 256 + t;
    lds[t] = (i < N_NODES) ? counts[i] : 0;
    __syncthreads();
    #pragma unroll
    for (int off = 128; off > 0; off >>= 1) {
        if (t < off) lds[t] += lds[t + off];
        __syncthreads();
    }
    if (t == 0) bsum[blockIdx.x] = lds[0];
}

// ---------------- K2b: scan block sums + relation offsets ----------------
__global__ __launch_bounds__(256) void k2b_scan(const int* __restrict__ relhist,
                                                const int* __restrict__ bsum,
                                                int* __restrict__ bbase,
                                                int* __restrict__ roff,
                                                int* __restrict__ relcur,
                                                int* __restrict__ tb,
                                                int* __restrict__ dst_off)
{
    __shared__ int lds[256];
    const int t = threadIdx.x;
    int v = (t < NSCAN_BLKS) ? bsum[t] : 0;
    lds[t] = v;
    __syncthreads();
    #pragma unroll
    for (int off = 1; off < 256; off <<= 1) {
        int u = (t >= off) ? lds[t - off] : 0;
        __syncthreads();
        lds[t] += u;
        __syncthreads();
    }
    if (t < NSCAN_BLKS) bbase[t] = lds[t] - v;   // exclusive base
    if (t == 0) {
        dst_off[N_NODES] = lds[255];             // total (= N_EDGES)
        int run = 0, trun = 0;
        #pragma unroll
        for (int r = 0; r < N_RELS; ++r) {
            roff[r] = run; relcur[r] = run; tb[r] = trun;
            int c = relhist[r];
            run += c; trun += (c + TILE_M - 1) / TILE_M;
        }
        roff[N_RELS] = run; tb[N_RELS] = trun;
    }
}

// ---------------- K2c: per-block scan + base -> dst offsets ----------------
__global__ __launch_bounds__(256) void k2c_off(const int* __restrict__ counts,
                                               const int* __restrict__ bbase,
                                               int* __restrict__ dst_off,
                                               int* __restrict__ dstcur)
{
    __shared__ int lds[256];
    const int t = threadIdx.x;
    const int i = blockIdx.x * 256 + t;
    int v = (i < N_NODES) ? counts[i] : 0;
    lds[t] = v;
    __syncthreads();
    #pragma unroll
    for (int off = 1; off < 256; off <<= 1) {
        int u = (t >= off) ? lds[t - off] : 0;
        __syncthreads();
        lds[t] += u;
        __syncthreads();
    }
    if (i < N_NODES) {
        int excl = bbase[blockIdx.x] + lds[t] - v;
        dst_off[i] = excl;
        dstcur[i]  = excl;
    }
}

// ---------------- K3: scatter ----------------
__global__ __launch_bounds__(256) void k3_scatter(const int* __restrict__ src,
                                                  const int* __restrict__ dst,
                                                  const int* __restrict__ et,
                                                  int* __restrict__ relcur,
                                                  int* __restrict__ dstcur,
                                                  int* __restrict__ relsrc,
                                                  int* __restrict__ csr_y)
{
    __shared__ int lh[N_RELS];
    __shared__ int lbase[N_RELS];
    const int t = threadIdx.x;
    if (t < N_RELS) lh[t] = 0;
    __syncthreads();
    const int e = blockIdx.x * 256 + t;
    const int r = et[e], s = src[e], d = dst[e];
    const int slot = atomicAdd(&lh[r], 1);
    __syncthreads();
    if (t < N_RELS && lh[t] > 0) lbase[t] = atomicAdd(&relcur[t], lh[t]);
    __syncthreads();
    const int j = lbase[r] + slot;
    relsrc[j] = s;
    const int p = atomicAdd(&dstcur[d], 1);
    csr_y[p] = j;
}

// ---------------- K4: per-relation GEMM via MFMA -> Y fp16 ----------------
__global__ __launch_bounds__(256) void k4_gemm(const float* __restrict__ feat,
                                               const _Float16* __restrict__ wT,
                                               const int* __restrict__ relsrc,
                                               const int* __restrict__ roff,
                                               const int* __restrict__ tb,
                                               _Float16* __restrict__ Y)
{
    __shared__ _Float16 aT[TILE_M * 64];   // XOR-swizzled [row][k]
    __shared__ _Float16 wL[64 * 64];       // XOR-swizzled [out][k]
    const int b = blockIdx.x, t = threadIdx.x;

    int r = -1, ti = 0, t0 = 0;
    #pragma unroll
    for (int q = 0; q < N_RELS; ++q) {
        int t1 = tb[q + 1];
        if (b >= t0 && b < t1) { r = q; ti = b - t0; }
        t0 = t1;
    }
    if (r < 0) return;
    const int segstart = roff[r], segend = roff[r + 1];
    const int rowbase = segstart + ti * TILE_M;

    {
        const _Float16* wsrc = wT + (size_t)r * 4096;
        #pragma unroll
        for (int it = 0; it < 2; ++it) {
            int L8 = it * 256 + t;
            int o = L8 >> 3, kcol = (L8 & 7) * 8;
            int baddr = (o * 128 + kcol * 2) ^ ((o & 7) << 4);
            *reinterpret_cast<half8*>(reinterpret_cast<char*>(wL) + baddr) =
                *reinterpret_cast<const half8*>(wsrc + L8 * 8);
        }
    }
    {
        const int j = rowbase + t;
        const int sidx = (j < segend) ? relsrc[j] : 0;
        const float4* frow = reinterpret_cast<const float4*>(feat + (size_t)sidx * 64);
        #pragma unroll
        for (int c = 0; c < 4; ++c) {
            float4 f0 = frow[c*4+0], f1 = frow[c*4+1], f2 = frow[c*4+2], f3 = frow[c*4+3];
            half8 h0, h1;
            h0[0]=(_Float16)f0.x; h0[1]=(_Float16)f0.y; h0[2]=(_Float16)f0.z; h0[3]=(_Float16)f0.w;
            h0[4]=(_Float16)f1.x; h0[5]=(_Float16)f1.y; h0[6]=(_Float16)f1.z; h0[7]=(_Float16)f1.w;
            h1[0]=(_Float16)f2.x; h1[1]=(_Float16)f2.y; h1[2]=(_Float16)f2.z; h1[3]=(_Float16)f2.w;
            h1[4]=(_Float16)f3.x; h1[5]=(_Float16)f3.y; h1[6]=(_Float16)f3.z; h1[7]=(_Float16)f3.w;
            int base = t * 128 + c * 32;
            int a0 = (base)      ^ ((t & 7) << 4);
            int a1 = (base + 16) ^ ((t & 7) << 4);
            *reinterpret_cast<half8*>(reinterpret_cast<char*>(aT) + a0) = h0;
            *reinterpret_cast<half8*>(reinterpret_cast<char*>(aT) + a1) = h1;
        }
    }
    __syncthreads();

    const int wid = t >> 6, l = t & 63;
    const int lrow = l & 15, lkb = l >> 4;
    f32x4 acc[4][4] = {};
    #pragma unroll
    for (int ks = 0; ks < 2; ++ks) {
        half8 af[4], bfr[4];
        #pragma unroll
        for (int rt = 0; rt < 4; ++rt) {
            int row = wid * 64 + rt * 16 + lrow;
            int baddr = (row * 128 + ks * 64 + lkb * 16) ^ ((row & 7) << 4);
            af[rt] = *reinterpret_cast<const half8*>(reinterpret_cast<const char*>(aT) + baddr);
        }
        #pragma unroll
        for (int ct = 0; ct < 4; ++ct) {
            int n = ct * 16 + lrow;
            int baddr = (n * 128 + ks * 64 + lkb * 16) ^ ((n & 7) << 4);
            bfr[ct] = *reinterpret_cast<const half8*>(reinterpret_cast<const char*>(wL) + baddr);
        }
        #pragma unroll
        for (int rt = 0; rt < 4; ++rt)
            #pragma unroll
            for (int ct = 0; ct < 4; ++ct)
                acc[rt][ct] = __builtin_amdgcn_mfma_f32_16x16x32_f16(af[rt], bfr[ct], acc[rt][ct], 0, 0, 0);
    }
    #pragma unroll
    for (int rt = 0; rt < 4; ++rt) {
        int rowg = rowbase + wid * 64 + rt * 16 + (l >> 4) * 4;
        #pragma unroll
        for (int ct = 0; ct < 4; ++ct) {
            int col = ct * 16 + lrow;
            #pragma unroll
            for (int reg = 0; reg < 4; ++reg) {
                int row = rowg + reg;
                if (row < segend)
                    Y[(size_t)row * 64 + col] = (_Float16)acc[rt][ct][reg];
            }
        }
    }
}

// ---------------- K5: dst-CSR gather reduce ----------------
__global__ __launch_bounds__(256) void k5_reduce(const _Float16* __restrict__ Y,
                                                 const int* __restrict__ csr_y,
                                                 const int* __restrict__ dst_off,
                                                 float* __restrict__ out)
{
    const int wid = threadIdx.x >> 6, l = threadIdx.x & 63;
    const int n = blockIdx.x * 4 + wid;
    if (n >= N_NODES) return;
    const int p0 = dst_off[n], p1 = dst_off[n + 1];
    float acc = 0.f;
    int p = p0;
    for (; p + 4 <= p1; p += 4) {
        int ja = csr_y[p], jb = csr_y[p+1], jc = csr_y[p+2], jd = csr_y[p+3];
        acc += (float)Y[(size_t)ja * 64 + l] + (float)Y[(size_t)jb * 64 + l]
             + (float)Y[(size_t)jc * 64 + l] + (float)Y[(size_t)jd * 64 + l];
    }
    for (; p < p1; ++p)
        acc += (float)Y[(size_t)csr_y[p] * 64 + l];
    out[(size_t)n * 64 + l] = acc;
}

extern "C" void kernel_launch(void* const* d_in, const int* in_sizes, int n_in,
                              void* d_out, int out_size, void* d_ws, size_t ws_size,
                              hipStream_t stream) {
    const float* feat   = (const float*)d_in[0];
    const float* weight = (const float*)d_in[1];
    const int*   src    = (const int*)d_in[2];
    const int*   dst    = (const int*)d_in[3];
    const int*   et     = (const int*)d_in[4];
    float*       out    = (float*)d_out;

    if (ws_size < (size_t)WS_REQ) {
        hipMemsetAsync(d_out, 0, (size_t)out_size * sizeof(float), stream);
        hipLaunchKernelGGL(rgcn_edge_atomic, dim3(4096), dim3(256), 0, stream,
                           feat, weight, src, dst, et, out, N_EDGES / 4);
        return;
    }

    char* ws = (char*)d_ws;
    int*       relhist = (int*)(ws + OFF_RELHIST);
    int*       relcur  = (int*)(ws + OFF_RELCUR);
    int*       roff    = (int*)(ws + OFF_ROFF);
    int*       tb      = (int*)(ws + OFF_TB);
    int*       bsum    = (int*)(ws + OFF_BSUM);
    int*       bbase   = (int*)(ws + OFF_BBASE);
    int*       counts  = (int*)(ws + OFF_COUNTS);
    int*       dst_off = (int*)(ws + OFF_DSTOFF);
    int*       dstcur  = (int*)(ws + OFF_DSTCUR);
    int*       relsrc  = (int*)(ws + OFF_RELSRC);
    int*       csr_y   = (int*)(ws + OFF_CSRY);
    _Float16*  wT      = (_Float16*)(ws + OFF_WT_A);
    _Float16*  Y       = (_Float16*)(ws + OFF_Y);

    hipMemsetAsync(relhist, 0, 128, stream);
    hipMemsetAsync(counts, 0, (size_t)N_NODES * sizeof(int), stream);

    hipLaunchKernelGGL(k0_wt,      dim3(N_RELS),        dim3(256),  0, stream, weight, wT);
    hipLaunchKernelGGL(k1_hist,    dim3(N_EDGES / 256), dim3(256),  0, stream, et, dst, relhist, counts);
    hipLaunchKernelGGL(k2a_bsum,   dim3(NSCAN_BLKS),    dim3(256),  0, stream, counts, bsum);
    hipLaunchKernelGGL(k2b_scan,   dim3(1),             dim3(256),  0, stream, relhist, bsum, bbase, roff, relcur, tb, dst_off);
    hipLaunchKernelGGL(k2c_off,    dim3(NSCAN_BLKS),    dim3(256),  0, stream, counts, bbase, dst_off, dstcur);
    hipLaunchKernelGGL(k3_scatter, dim3(N_EDGES / 256), dim3(256),  0, stream, src, dst, et, relcur, dstcur, relsrc, csr_y);
    const int max_tiles = N_EDGES / TILE_M + N_RELS;
    hipLaunchKernelGGL(k4_gemm,    dim3(max_tiles),     dim3(256),  0, stream, feat, wT, relsrc, roff, tb, Y);
    hipLaunchKernelGGL(k5_reduce,  dim3((N_NODES + 3) / 4), dim3(256), 0, stream, Y, csr_y, dst_off, out);
}

// Round 4
// 149.552 us; speedup vs baseline: 5.4455x; 1.6581x over previous
//
#include <hip/hip_runtime.h>
#include <hip/hip_bf16.h>

#define N_NODES 50000
#define N_EDGES 800000
#define N_RELS  32
#define D       64
#define TILE_M  256
#define NBKT    196                         // ceil(50000/256)
#define EPB     2048                        // edges per block in kA/kC
#define NEBLK   ((N_EDGES + EPB - 1) / EPB) // 391

typedef _Float16 half8 __attribute__((ext_vector_type(8)));
typedef float    f32x4 __attribute__((ext_vector_type(4)));

// ---------------- workspace layout (bytes) ----------------
#define OFF_RELHIST 0u          // 32 int
#define OFF_BKTHIST 128u        // 196 int   (memset [0,912))
#define OFF_RELCUR  1024u       // 32 int
#define OFF_BKTCUR  1152u       // 196 int
#define OFF_ROFF    1936u       // 33 int
#define OFF_TB      2080u       // 33 int
#define OFF_BKTOFF  2224u       // 197 int
#define OFF_DSTOFF  3072u       // 50001 int
#define OFF_RELSRC  203776u     // 800000 int
#define OFF_CSRY    3403776u    // 800000 int
#define OFF_WT      6603776u    // 32*64*64 fp16
#define OFF_Y       6865920u    // 800000*64 fp16 (bucketed[] aliases its head)
#define WS_REQ      109265920u

// ---------------- fallback: atomic scatter path ----------------
__global__ __launch_bounds__(256) void rgcn_edge_atomic(
    const float* __restrict__ feat, const float* __restrict__ weight,
    const int* __restrict__ src, const int* __restrict__ dst,
    const int* __restrict__ et, float* __restrict__ out, int nquads)
{
    const int tid  = blockIdx.x * blockDim.x + threadIdx.x;
    const int wave = tid >> 6, lane = tid & 63;
    const int grp = lane >> 4, lg = lane & 15;
    const int wave_stride = (gridDim.x * blockDim.x) >> 6;
    for (int q = wave; q < nquads; q += wave_stride) {
        const int e = q * 4 + grp;
        const int s = src[e], d = dst[e], r = et[e];
        const float* w = weight + (size_t)r * D * D + lg * 4;
        float ax = 0.f, ay = 0.f, az = 0.f, aw = 0.f;
        #pragma unroll
        for (int i4 = 0; i4 < D / 4; ++i4) {
            const float4 f  = *reinterpret_cast<const float4*>(feat + (size_t)s * D + i4 * 4);
            const float4 w0 = *reinterpret_cast<const float4*>(w + (i4 * 4 + 0) * D);
            const float4 w1 = *reinterpret_cast<const float4*>(w + (i4 * 4 + 1) * D);
            const float4 w2 = *reinterpret_cast<const float4*>(w + (i4 * 4 + 2) * D);
            const float4 w3 = *reinterpret_cast<const float4*>(w + (i4 * 4 + 3) * D);
            ax += f.x*w0.x; ay += f.x*w0.y; az += f.x*w0.z; aw += f.x*w0.w;
            ax += f.y*w1.x; ay += f.y*w1.y; az += f.y*w1.z; aw += f.y*w1.w;
            ax += f.z*w2.x; ay += f.z*w2.y; az += f.z*w2.z; aw += f.z*w2.w;
            ax += f.w*w3.x; ay += f.w*w3.y; az += f.w*w3.z; aw += f.w*w3.w;
        }
        float* orow = out + (size_t)d * D + lg * 4;
        atomicAdd(orow + 0, ax); atomicAdd(orow + 1, ay);
        atomicAdd(orow + 2, az); atomicAdd(orow + 3, aw);
    }
}

// ---------------- K0: W -> W^T fp16 (wT[r][o][k]) ----------------
__global__ __launch_bounds__(256) void k0_wt(const float* __restrict__ w,
                                             _Float16* __restrict__ wT)
{
    const int r = blockIdx.x, t = threadIdx.x;
    #pragma unroll
    for (int i = 0; i < 16; ++i) {
        int oidx = i * 256 + t;
        int o = oidx >> 6, k = oidx & 63;
        wT[(size_t)r * 4096 + oidx] = (_Float16)w[(size_t)r * 4096 + k * 64 + o];
    }
}

// ---------------- kA: LDS-aggregated rel + bucket histograms ----------------
__global__ __launch_bounds__(256) void kA_hist(const int* __restrict__ et,
                                               const int* __restrict__ dst,
                                               int* __restrict__ relhist,
                                               int* __restrict__ bkthist)
{
    __shared__ int lh[N_RELS];
    __shared__ int lb[NBKT];
    const int t = threadIdx.x;
    if (t < N_RELS) lh[t] = 0;
    if (t < NBKT)   lb[t] = 0;
    __syncthreads();
    const int base = blockIdx.x * EPB + t * 8;
    #pragma unroll
    for (int i = 0; i < 8; ++i) {
        int e = base + i;
        if (e < N_EDGES) {
            atomicAdd(&lh[et[e]], 1);
            atomicAdd(&lb[dst[e] >> 8], 1);
        }
    }
    __syncthreads();
    if (t < N_RELS && lh[t]) atomicAdd(&relhist[t], lh[t]);
    if (t < NBKT   && lb[t]) atomicAdd(&bkthist[t], lb[t]);
}

// ---------------- kB: parallel scans (rel offsets, tile table, bucket offs) -
__global__ __launch_bounds__(256) void kB_scan(const int* __restrict__ relhist,
                                               const int* __restrict__ bkthist,
                                               int* __restrict__ roff,
                                               int* __restrict__ relcur,
                                               int* __restrict__ tb,
                                               int* __restrict__ bktoff,
                                               int* __restrict__ bktcur,
                                               int* __restrict__ dst_off)
{
    __shared__ int s[256];
    const int t = threadIdx.x;
    // --- relation counts scan ---
    int v = (t < N_RELS) ? relhist[t] : 0;
    s[t] = v; __syncthreads();
    #pragma unroll
    for (int off = 1; off < 32; off <<= 1) {
        int u = (t >= off && t < N_RELS) ? s[t - off] : 0;
        __syncthreads(); s[t] += u; __syncthreads();
    }
    if (t < N_RELS) { int ex = s[t] - v; roff[t] = ex; relcur[t] = ex; }
    if (t == N_RELS - 1) roff[N_RELS] = s[t];
    __syncthreads();
    // --- tile table scan ---
    int w = (v + TILE_M - 1) / TILE_M;
    s[t] = (t < N_RELS) ? w : 0; __syncthreads();
    #pragma unroll
    for (int off = 1; off < 32; off <<= 1) {
        int u = (t >= off && t < N_RELS) ? s[t - off] : 0;
        __syncthreads(); s[t] += u; __syncthreads();
    }
    if (t < N_RELS) tb[t] = s[t] - w;
    if (t == N_RELS - 1) tb[N_RELS] = s[t];
    __syncthreads();
    // --- bucket counts scan (196 <= 256) ---
    int v2 = (t < NBKT) ? bkthist[t] : 0;
    s[t] = v2; __syncthreads();
    #pragma unroll
    for (int off = 1; off < 256; off <<= 1) {
        int u = (t >= off) ? s[t - off] : 0;
        __syncthreads(); s[t] += u; __syncthreads();
    }
    if (t < NBKT) { int ex = s[t] - v2; bktoff[t] = ex; bktcur[t] = ex; }
    if (t == NBKT - 1) bktoff[NBKT] = s[t];
    if (t == 0) dst_off[N_NODES] = N_EDGES;
}

// ---------------- kC: rel-scatter + dst-bucket scatter (LDS-aggregated) -----
__global__ __launch_bounds__(256) void kC_scatter(const int* __restrict__ src,
                                                  const int* __restrict__ dst,
                                                  const int* __restrict__ et,
                                                  int* __restrict__ relcur,
                                                  int* __restrict__ bktcur,
                                                  int* __restrict__ relsrc,
                                                  int* __restrict__ bucketed)
{
    __shared__ int lh[N_RELS],  lbase[N_RELS];
    __shared__ int lb[NBKT],    lbase2[NBKT];
    const int t = threadIdx.x;
    if (t < N_RELS) lh[t] = 0;
    if (t < NBKT)   lb[t] = 0;
    __syncthreads();
    const int base = blockIdx.x * EPB + t * 8;
    int r_[8], b_[8], s_[8], d_[8], sl[8], sl2[8];
    #pragma unroll
    for (int i = 0; i < 8; ++i) {
        int e = base + i;
        if (e < N_EDGES) {
            r_[i] = et[e]; s_[i] = src[e]; d_[i] = dst[e];
            b_[i] = d_[i] >> 8;
            sl[i]  = atomicAdd(&lh[r_[i]], 1);
            sl2[i] = atomicAdd(&lb[b_[i]], 1);
        }
    }
    __syncthreads();
    if (t < N_RELS && lh[t]) lbase[t]  = atomicAdd(&relcur[t], lh[t]);
    if (t < NBKT   && lb[t]) lbase2[t] = atomicAdd(&bktcur[t], lb[t]);
    __syncthreads();
    #pragma unroll
    for (int i = 0; i < 8; ++i) {
        int e = base + i;
        if (e < N_EDGES) {
            int j = lbase[r_[i]] + sl[i];
            relsrc[j] = s_[i];
            bucketed[lbase2[b_[i]] + sl2[i]] = ((d_[i] & 255) << 20) | j;
        }
    }
}

// ---------------- kD: per-bucket counting sort -> dst_off + csr_y -----------
__global__ __launch_bounds__(256) void kD_csr(const int* __restrict__ bucketed,
                                              const int* __restrict__ bktoff,
                                              int* __restrict__ csr_y,
                                              int* __restrict__ dst_off)
{
    __shared__ int hist[256];
    __shared__ int s[256];
    const int b = blockIdx.x, t = threadIdx.x;
    const int lo = bktoff[b], hi = bktoff[b + 1];
    hist[t] = 0; __syncthreads();
    for (int p = lo + t; p < hi; p += 256)
        atomicAdd(&hist[bucketed[p] >> 20], 1);
    __syncthreads();
    int v = hist[t];
    s[t] = v; __syncthreads();
    #pragma unroll
    for (int off = 1; off < 256; off <<= 1) {
        int u = (t >= off) ? s[t - off] : 0;
        __syncthreads(); s[t] += u; __syncthreads();
    }
    int ex = lo + s[t] - v;
    int n = b * 256 + t;
    if (n < N_NODES) dst_off[n] = ex;
    hist[t] = ex;                      // reuse as per-node cursor
    __syncthreads();
    for (int p = lo + t; p < hi; p += 256) {
        int key = bucketed[p];
        int pos = atomicAdd(&hist[key >> 20], 1);
        csr_y[pos] = key & 0xFFFFF;
    }
}

// ---------------- K4: per-relation GEMM via MFMA -> Y fp16 ----------------
__global__ __launch_bounds__(256) void k4_gemm(const float* __restrict__ feat,
                                               const _Float16* __restrict__ wT,
                                               const int* __restrict__ relsrc,
                                               const int* __restrict__ roff,
                                               const int* __restrict__ tb,
                                               _Float16* __restrict__ Y)
{
    __shared__ _Float16 aT[TILE_M * 64];   // XOR-swizzled [row][k]
    __shared__ _Float16 wL[64 * 64];       // XOR-swizzled [out][k]
    const int b = blockIdx.x, t = threadIdx.x;

    int r = -1, ti = 0, t0 = 0;
    #pragma unroll
    for (int q = 0; q < N_RELS; ++q) {
        int t1 = tb[q + 1];
        if (b >= t0 && b < t1) { r = q; ti = b - t0; }
        t0 = t1;
    }
    if (r < 0) return;
    const int segstart = roff[r], segend = roff[r + 1];
    const int rowbase = segstart + ti * TILE_M;

    {
        const _Float16* wsrc = wT + (size_t)r * 4096;
        #pragma unroll
        for (int it = 0; it < 2; ++it) {
            int L8 = it * 256 + t;
            int o = L8 >> 3, kcol = (L8 & 7) * 8;
            int baddr = (o * 128 + kcol * 2) ^ ((o & 7) << 4);
            *reinterpret_cast<half8*>(reinterpret_cast<char*>(wL) + baddr) =
                *reinterpret_cast<const half8*>(wsrc + L8 * 8);
        }
    }
    {
        const int j = rowbase + t;
        const int sidx = (j < segend) ? relsrc[j] : 0;
        const float4* frow = reinterpret_cast<const float4*>(feat + (size_t)sidx * 64);
        #pragma unroll
        for (int c = 0; c < 4; ++c) {
            float4 f0 = frow[c*4+0], f1 = frow[c*4+1], f2 = frow[c*4+2], f3 = frow[c*4+3];
            half8 h0, h1;
            h0[0]=(_Float16)f0.x; h0[1]=(_Float16)f0.y; h0[2]=(_Float16)f0.z; h0[3]=(_Float16)f0.w;
            h0[4]=(_Float16)f1.x; h0[5]=(_Float16)f1.y; h0[6]=(_Float16)f1.z; h0[7]=(_Float16)f1.w;
            h1[0]=(_Float16)f2.x; h1[1]=(_Float16)f2.y; h1[2]=(_Float16)f2.z; h1[3]=(_Float16)f2.w;
            h1[4]=(_Float16)f3.x; h1[5]=(_Float16)f3.y; h1[6]=(_Float16)f3.z; h1[7]=(_Float16)f3.w;
            int base = t * 128 + c * 32;
            int a0 = (base)      ^ ((t & 7) << 4);
            int a1 = (base + 16) ^ ((t & 7) << 4);
            *reinterpret_cast<half8*>(reinterpret_cast<char*>(aT) + a0) = h0;
            *reinterpret_cast<half8*>(reinterpret_cast<char*>(aT) + a1) = h1;
        }
    }
    __syncthreads();

    const int wid = t >> 6, l = t & 63;
    const int lrow = l & 15, lkb = l >> 4;
    f32x4 acc[4][4] = {};
    #pragma unroll
    for (int ks = 0; ks < 2; ++ks) {
        half8 af[4], bfr[4];
        #pragma unroll
        for (int rt = 0; rt < 4; ++rt) {
            int row = wid * 64 + rt * 16 + lrow;
            int baddr = (row * 128 + ks * 64 + lkb * 16) ^ ((row & 7) << 4);
            af[rt] = *reinterpret_cast<const half8*>(reinterpret_cast<const char*>(aT) + baddr);
        }
        #pragma unroll
        for (int ct = 0; ct < 4; ++ct) {
            int n = ct * 16 + lrow;
            int baddr = (n * 128 + ks * 64 + lkb * 16) ^ ((n & 7) << 4);
            bfr[ct] = *reinterpret_cast<const half8*>(reinterpret_cast<const char*>(wL) + baddr);
        }
        #pragma unroll
        for (int rt = 0; rt < 4; ++rt)
            #pragma unroll
            for (int ct = 0; ct < 4; ++ct)
                acc[rt][ct] = __builtin_amdgcn_mfma_f32_16x16x32_f16(af[rt], bfr[ct], acc[rt][ct], 0, 0, 0);
    }
    #pragma unroll
    for (int rt = 0; rt < 4; ++rt) {
        int rowg = rowbase + wid * 64 + rt * 16 + (l >> 4) * 4;
        #pragma unroll
        for (int ct = 0; ct < 4; ++ct) {
            int col = ct * 16 + lrow;
            #pragma unroll
            for (int reg = 0; reg < 4; ++reg) {
                int row = rowg + reg;
                if (row < segend)
                    Y[(size_t)row * 64 + col] = (_Float16)acc[rt][ct][reg];
            }
        }
    }
}

// ---------------- K5: dst-CSR gather reduce ----------------
__global__ __launch_bounds__(256) void k5_reduce(const _Float16* __restrict__ Y,
                                                 const int* __restrict__ csr_y,
                                                 const int* __restrict__ dst_off,
                                                 float* __restrict__ out)
{
    const int wid = threadIdx.x >> 6, l = threadIdx.x & 63;
    const int n = blockIdx.x * 4 + wid;
    if (n >= N_NODES) return;
    const int p0 = dst_off[n], p1 = dst_off[n + 1];
    float acc = 0.f;
    int p = p0;
    for (; p + 4 <= p1; p += 4) {
        int ja = csr_y[p], jb = csr_y[p+1], jc = csr_y[p+2], jd = csr_y[p+3];
        acc += (float)Y[(size_t)ja * 64 + l] + (float)Y[(size_t)jb * 64 + l]
             + (float)Y[(size_t)jc * 64 + l] + (float)Y[(size_t)jd * 64 + l];
    }
    for (; p < p1; ++p)
        acc += (float)Y[(size_t)csr_y[p] * 64 + l];
    out[(size_t)n * 64 + l] = acc;
}

extern "C" void kernel_launch(void* const* d_in, const int* in_sizes, int n_in,
                              void* d_out, int out_size, void* d_ws, size_t ws_size,
                              hipStream_t stream) {
    const float* feat   = (const float*)d_in[0];
    const float* weight = (const float*)d_in[1];
    const int*   src    = (const int*)d_in[2];
    const int*   dst    = (const int*)d_in[3];
    const int*   et     = (const int*)d_in[4];
    float*       out    = (float*)d_out;

    if (ws_size < (size_t)WS_REQ) {
        hipMemsetAsync(d_out, 0, (size_t)out_size * sizeof(float), stream);
        hipLaunchKernelGGL(rgcn_edge_atomic, dim3(4096), dim3(256), 0, stream,
                           feat, weight, src, dst, et, out, N_EDGES / 4);
        return;
    }

    char* ws = (char*)d_ws;
    int*       relhist  = (int*)(ws + OFF_RELHIST);
    int*       bkthist  = (int*)(ws + OFF_BKTHIST);
    int*       relcur   = (int*)(ws + OFF_RELCUR);
    int*       bktcur   = (int*)(ws + OFF_BKTCUR);
    int*       roff     = (int*)(ws + OFF_ROFF);
    int*       tb       = (int*)(ws + OFF_TB);
    int*       bktoff   = (int*)(ws + OFF_BKTOFF);
    int*       dst_off  = (int*)(ws + OFF_DSTOFF);
    int*       relsrc   = (int*)(ws + OFF_RELSRC);
    int*       csr_y    = (int*)(ws + OFF_CSRY);
    _Float16*  wT       = (_Float16*)(ws + OFF_WT);
    _Float16*  Y        = (_Float16*)(ws + OFF_Y);
    int*       bucketed = (int*)(ws + OFF_Y);   // aliases Y head; dead before k4

    hipMemsetAsync(ws, 0, 912, stream);         // relhist + bkthist

    hipLaunchKernelGGL(k0_wt,      dim3(N_RELS), dim3(256), 0, stream, weight, wT);
    hipLaunchKernelGGL(kA_hist,    dim3(NEBLK),  dim3(256), 0, stream, et, dst, relhist, bkthist);
    hipLaunchKernelGGL(kB_scan,    dim3(1),      dim3(256), 0, stream, relhist, bkthist, roff, relcur, tb, bktoff, bktcur, dst_off);
    hipLaunchKernelGGL(kC_scatter, dim3(NEBLK),  dim3(256), 0, stream, src, dst, et, relcur, bktcur, relsrc, bucketed);
    hipLaunchKernelGGL(kD_csr,     dim3(NBKT),   dim3(256), 0, stream, bucketed, bktoff, csr_y, dst_off);
    const int max_tiles = N_EDGES / TILE_M + N_RELS;
    hipLaunchKernelGGL(k4_gemm,    dim3(max_tiles),         dim3(256), 0, stream, feat, wT, relsrc, roff, tb, Y);
    hipLaunchKernelGGL(k5_reduce,  dim3((N_NODES + 3) / 4), dim3(256), 0, stream, Y, csr_y, dst_off, out);
}